// Round 1
// baseline (562.749 us; speedup 1.0000x reference)
//
#include <hip/hip_runtime.h>
#include <hip/hip_bf16.h>
#include <math.h>

#define D_DIM 1024
#define F_DIM 2816
#define E_NUM 8

#define BM 128
#define BN 64
#define BK 64

typedef __attribute__((ext_vector_type(4))) float f32x4;
typedef __attribute__((ext_vector_type(8))) short short8;

__device__ __forceinline__ unsigned short f2bf(float f) {
    unsigned u = __float_as_uint(f);
    u = (u + 0x7FFFu + ((u >> 16) & 1u)) >> 16;
    return (unsigned short)u;
}

__device__ __forceinline__ float gelu_erf(float z) {
    return 0.5f * z * (1.0f + erff(z * 0.70710678118654752f));
}

__device__ __forceinline__ int swz(int row, int kb) {
    return row * 128 + (kb ^ ((row & 7) << 4));
}

__device__ __forceinline__ uint4 pack8(const unsigned short* h) {
    uint4 r;
    r.x = (unsigned)h[0] | ((unsigned)h[1] << 16);
    r.y = (unsigned)h[2] | ((unsigned)h[3] << 16);
    r.z = (unsigned)h[4] | ((unsigned)h[5] << 16);
    r.w = (unsigned)h[6] | ((unsigned)h[7] << 16);
    return r;
}

// ---------------- router: scores, softmax, top-2, x->bf16 ----------------
__global__ __launch_bounds__(64) void router_kernel(
    const float* __restrict__ x, const float* __restrict__ rw,
    unsigned short* __restrict__ xbf, int* __restrict__ tk_idx,
    float* __restrict__ tk_w, int* __restrict__ counts)
{
    int t = blockIdx.x;
    int lane = threadIdx.x;
    const float* xr = x + (size_t)t * D_DIM;
    float acc[E_NUM];
#pragma unroll
    for (int e = 0; e < E_NUM; ++e) acc[e] = 0.f;
#pragma unroll
    for (int i = 0; i < D_DIM / 64; ++i) {
        int d = lane + 64 * i;
        float xv = xr[d];
        xbf[(size_t)t * D_DIM + d] = f2bf(xv);
        const float* rp = rw + (size_t)d * E_NUM;
#pragma unroll
        for (int e = 0; e < E_NUM; ++e) acc[e] += xv * rp[e];
    }
#pragma unroll
    for (int e = 0; e < E_NUM; ++e) {
#pragma unroll
        for (int s = 32; s > 0; s >>= 1) acc[e] += __shfl_xor(acc[e], s, 64);
    }
    float mx = acc[0];
#pragma unroll
    for (int e = 1; e < E_NUM; ++e) mx = fmaxf(mx, acc[e]);
    float p[E_NUM], se = 0.f;
#pragma unroll
    for (int e = 0; e < E_NUM; ++e) { p[e] = expf(acc[e] - mx); se += p[e]; }
    float inv = 1.f / se;
    int e1 = 0;
#pragma unroll
    for (int e = 1; e < E_NUM; ++e) if (p[e] > p[e1]) e1 = e;
    int e2 = (e1 == 0) ? 1 : 0;
#pragma unroll
    for (int e = 0; e < E_NUM; ++e) if (e != e1 && p[e] > p[e2]) e2 = e;
    if (lane == 0) {
        tk_idx[2 * t] = e1; tk_idx[2 * t + 1] = e2;
        tk_w[2 * t] = p[e1] * inv; tk_w[2 * t + 1] = p[e2] * inv;
        atomicAdd(&counts[e1], 1);
        atomicAdd(&counts[e2], 1);
    }
}

// ---------------- scan: offsets + tile map ----------------
__global__ void scan_kernel(const int* __restrict__ counts, int* __restrict__ offsets,
                            int* __restrict__ tile_e, int* __restrict__ tile_row,
                            int* __restrict__ n_mt)
{
    if (threadIdx.x != 0) return;
    int off = 0, nt = 0;
    for (int e = 0; e < E_NUM; ++e) {
        offsets[e] = off;
        int ne = counts[e];
        int nti = (ne + BM - 1) / BM;
        for (int i = 0; i < nti; ++i) { tile_e[nt] = e; tile_row[nt] = off + i * BM; ++nt; }
        off += ne;
    }
    offsets[E_NUM] = off;
    *n_mt = nt;
}

// ---------------- compact: deterministic token-ordered pair lists ----------------
__global__ __launch_bounds__(256) void compact_kernel(
    const int* __restrict__ tk_idx, const int* __restrict__ offsets,
    int* __restrict__ pair_token, int* __restrict__ pair_pos, int T)
{
    int e = blockIdx.x;
    int tid = threadIdx.x;
    __shared__ int s[256];
    __shared__ int running;
    if (tid == 0) running = 0;
    __syncthreads();
    int base0 = offsets[e];
    for (int base = 0; base < T; base += 256) {
        int t = base + tid;
        int flag = 0, slot = -1;
        if (t < T) {
            int i0 = tk_idx[2 * t], i1 = tk_idx[2 * t + 1];
            slot = (i0 == e) ? 0 : ((i1 == e) ? 1 : -1);
            flag = (slot >= 0) ? 1 : 0;
        }
        s[tid] = flag;
        __syncthreads();
        for (int d = 1; d < 256; d <<= 1) {
            int v = (tid >= d) ? s[tid - d] : 0;
            __syncthreads();
            s[tid] += v;
            __syncthreads();
        }
        int total = s[255];
        int run = running;
        if (flag) {
            int pos = base0 + run + s[tid] - 1;
            pair_token[pos] = t;
            pair_pos[2 * t + slot] = pos;
        }
        __syncthreads();
        if (tid == 0) running += total;
        __syncthreads();
    }
}

// ---------------- grouped GEMM1 + GLU: h = gelu(x@w1) * (x@v1), bf16 out ----------------
__global__ __launch_bounds__(256) void gemm1_glu_kernel(
    const unsigned short* __restrict__ xbf,
    const float* __restrict__ w1, const float* __restrict__ v1,
    const int* __restrict__ pair_token, const int* __restrict__ offsets,
    const int* __restrict__ tile_e, const int* __restrict__ tile_row,
    const int* __restrict__ n_mt,
    unsigned short* __restrict__ hbf)
{
    int mt = blockIdx.x;
    if (mt >= *n_mt) return;
    int e = tile_e[mt];
    int row0 = tile_row[mt];
    int end = offsets[e + 1];
    int n0 = blockIdx.y * BN;

    __shared__ __align__(16) unsigned short As[BM * BK];
    __shared__ __align__(16) unsigned short Bs[2][BN * BK];

    int tid = threadIdx.x;
    int lane = tid & 63;
    int wid = tid >> 6;
    int wr = wid >> 1, wc = wid & 1;

    const float* Wp0 = w1 + (size_t)e * D_DIM * F_DIM;
    const float* Wp1 = v1 + (size_t)e * D_DIM * F_DIM;

    f32x4 acc[2][4][2];
#pragma unroll
    for (int a = 0; a < 2; ++a)
#pragma unroll
        for (int m = 0; m < 4; ++m)
#pragma unroll
            for (int n = 0; n < 2; ++n) acc[a][m][n] = (f32x4){0.f, 0.f, 0.f, 0.f};

    const unsigned short* arow[4];
#pragma unroll
    for (int i = 0; i < 4; ++i) {
        int c = tid + 256 * i;
        int row = c >> 3;
        int p = row0 + row;
        arow[i] = (p < end) ? (xbf + (size_t)pair_token[p] * D_DIM + (c & 7) * 8) : nullptr;
    }

    for (int kt = 0; kt < D_DIM / BK; ++kt) {
        int kbase = kt * BK;
        uint4 aC[4];
#pragma unroll
        for (int i = 0; i < 4; ++i) {
            if (arow[i]) aC[i] = *(const uint4*)(arow[i] + kbase);
            else aC[i] = (uint4){0u, 0u, 0u, 0u};
        }
        uint4 bC[2][2];
#pragma unroll
        for (int i = 0; i < 2; ++i) {
            int c = tid + 256 * i;
            int n = c & 63;
            int k8 = c >> 6;
            const float* s0 = Wp0 + (size_t)(kbase + k8 * 8) * F_DIM + n0 + n;
            const float* s1 = Wp1 + (size_t)(kbase + k8 * 8) * F_DIM + n0 + n;
            unsigned short h0[8], h1[8];
#pragma unroll
            for (int j = 0; j < 8; ++j) {
                h0[j] = f2bf(s0[(size_t)j * F_DIM]);
                h1[j] = f2bf(s1[(size_t)j * F_DIM]);
            }
            bC[0][i] = pack8(h0);
            bC[1][i] = pack8(h1);
        }
        __syncthreads();
#pragma unroll
        for (int i = 0; i < 4; ++i) {
            int c = tid + 256 * i;
            int row = c >> 3;
            int kb = (c & 7) * 16;
            *(uint4*)((char*)As + swz(row, kb)) = aC[i];
        }
#pragma unroll
        for (int i = 0; i < 2; ++i) {
            int c = tid + 256 * i;
            int n = c & 63;
            int kb = (c >> 6) * 16;
            *(uint4*)((char*)Bs[0] + swz(n, kb)) = bC[0][i];
            *(uint4*)((char*)Bs[1] + swz(n, kb)) = bC[1][i];
        }
        __syncthreads();
#pragma unroll
        for (int kk = 0; kk < 2; ++kk) {
            short8 af[4];
#pragma unroll
            for (int m = 0; m < 4; ++m) {
                int row = wr * 64 + m * 16 + (lane & 15);
                int kb = kk * 64 + (lane >> 4) * 16;
                af[m] = *(const short8*)((char*)As + swz(row, kb));
            }
            short8 bf0[2], bf1[2];
#pragma unroll
            for (int n = 0; n < 2; ++n) {
                int rn = wc * 32 + n * 16 + (lane & 15);
                int kb = kk * 64 + (lane >> 4) * 16;
                bf0[n] = *(const short8*)((char*)Bs[0] + swz(rn, kb));
                bf1[n] = *(const short8*)((char*)Bs[1] + swz(rn, kb));
            }
#pragma unroll
            for (int m = 0; m < 4; ++m)
#pragma unroll
                for (int n = 0; n < 2; ++n) {
                    acc[0][m][n] = __builtin_amdgcn_mfma_f32_16x16x32_bf16(af[m], bf0[n], acc[0][m][n], 0, 0, 0);
                    acc[1][m][n] = __builtin_amdgcn_mfma_f32_16x16x32_bf16(af[m], bf1[n], acc[1][m][n], 0, 0, 0);
                }
        }
    }
#pragma unroll
    for (int m = 0; m < 4; ++m) {
#pragma unroll
        for (int j = 0; j < 4; ++j) {
            int rl = wr * 64 + m * 16 + (lane >> 4) * 4 + j;
            int p = row0 + rl;
            if (p < end) {
#pragma unroll
                for (int n = 0; n < 2; ++n) {
                    float z1 = acc[0][m][n][j];
                    float z2 = acc[1][m][n][j];
                    float hv = gelu_erf(z1) * z2;
                    hbf[(size_t)p * F_DIM + n0 + wc * 32 + n * 16 + (lane & 15)] = f2bf(hv);
                }
            }
        }
    }
}

// ---------------- grouped GEMM2: y = h @ w2[e], fp32 per-pair out ----------------
__global__ __launch_bounds__(256) void gemm2_kernel(
    const unsigned short* __restrict__ hbf,
    const float* __restrict__ w2,
    const int* __restrict__ offsets,
    const int* __restrict__ tile_e, const int* __restrict__ tile_row,
    const int* __restrict__ n_mt,
    float* __restrict__ ypair)
{
    int mt = blockIdx.x;
    if (mt >= *n_mt) return;
    int e = tile_e[mt];
    int row0 = tile_row[mt];
    int end = offsets[e + 1];
    int n0 = blockIdx.y * BN;

    __shared__ __align__(16) unsigned short As[BM * BK];
    __shared__ __align__(16) unsigned short Bs[BN * BK];

    int tid = threadIdx.x;
    int lane = tid & 63;
    int wid = tid >> 6;
    int wr = wid >> 1, wc = wid & 1;

    const float* Wp = w2 + (size_t)e * F_DIM * D_DIM;

    f32x4 acc[4][2];
#pragma unroll
    for (int m = 0; m < 4; ++m)
#pragma unroll
        for (int n = 0; n < 2; ++n) acc[m][n] = (f32x4){0.f, 0.f, 0.f, 0.f};

    for (int kt = 0; kt < F_DIM / BK; ++kt) {
        int kbase = kt * BK;
        uint4 aC[4];
#pragma unroll
        for (int i = 0; i < 4; ++i) {
            int c = tid + 256 * i;
            int row = c >> 3;
            int p = row0 + row;
            if (p < end) aC[i] = *(const uint4*)(hbf + (size_t)p * F_DIM + kbase + (c & 7) * 8);
            else aC[i] = (uint4){0u, 0u, 0u, 0u};
        }
        uint4 bC[2];
#pragma unroll
        for (int i = 0; i < 2; ++i) {
            int c = tid + 256 * i;
            int n = c & 63;
            int k8 = c >> 6;
            const float* s0 = Wp + (size_t)(kbase + k8 * 8) * D_DIM + n0 + n;
            unsigned short h0[8];
#pragma unroll
            for (int j = 0; j < 8; ++j) h0[j] = f2bf(s0[(size_t)j * D_DIM]);
            bC[i] = pack8(h0);
        }
        __syncthreads();
#pragma unroll
        for (int i = 0; i < 4; ++i) {
            int c = tid + 256 * i;
            int row = c >> 3;
            int kb = (c & 7) * 16;
            *(uint4*)((char*)As + swz(row, kb)) = aC[i];
        }
#pragma unroll
        for (int i = 0; i < 2; ++i) {
            int c = tid + 256 * i;
            int n = c & 63;
            int kb = (c >> 6) * 16;
            *(uint4*)((char*)Bs + swz(n, kb)) = bC[i];
        }
        __syncthreads();
#pragma unroll
        for (int kk = 0; kk < 2; ++kk) {
            short8 af[4];
#pragma unroll
            for (int m = 0; m < 4; ++m) {
                int row = wr * 64 + m * 16 + (lane & 15);
                int kb = kk * 64 + (lane >> 4) * 16;
                af[m] = *(const short8*)((char*)As + swz(row, kb));
            }
            short8 bfr[2];
#pragma unroll
            for (int n = 0; n < 2; ++n) {
                int rn = wc * 32 + n * 16 + (lane & 15);
                int kb = kk * 64 + (lane >> 4) * 16;
                bfr[n] = *(const short8*)((char*)Bs + swz(rn, kb));
            }
#pragma unroll
            for (int m = 0; m < 4; ++m)
#pragma unroll
                for (int n = 0; n < 2; ++n)
                    acc[m][n] = __builtin_amdgcn_mfma_f32_16x16x32_bf16(af[m], bfr[n], acc[m][n], 0, 0, 0);
        }
    }
#pragma unroll
    for (int m = 0; m < 4; ++m) {
#pragma unroll
        for (int j = 0; j < 4; ++j) {
            int rl = wr * 64 + m * 16 + (lane >> 4) * 4 + j;
            int p = row0 + rl;
            if (p < end) {
#pragma unroll
                for (int n = 0; n < 2; ++n)
                    ypair[(size_t)p * D_DIM + n0 + wc * 32 + n * 16 + (lane & 15)] = acc[m][n][j];
            }
        }
    }
}

// ---------------- combine: out = bias + w0*y[p0] + w1*y[p1] ----------------
__global__ __launch_bounds__(256) void combine_kernel(
    const float* __restrict__ ypair, const int* __restrict__ pair_pos,
    const float* __restrict__ tk_w, const float* __restrict__ bias,
    float* __restrict__ out, int total)
{
    int idx = blockIdx.x * 256 + threadIdx.x;
    if (idx >= total) return;
    int t = idx >> 10;
    int d = idx & (D_DIM - 1);
    int p0 = pair_pos[2 * t], p1 = pair_pos[2 * t + 1];
    float r = bias[d] + tk_w[2 * t] * ypair[(size_t)p0 * D_DIM + d]
                      + tk_w[2 * t + 1] * ypair[(size_t)p1 * D_DIM + d];
    out[idx] = r;
}

__global__ void ws_too_small_kernel(float* out, int n) {
    int i = blockIdx.x * 256 + threadIdx.x;
    if (i < n) out[i] = 12345.0f;
}

extern "C" void kernel_launch(void* const* d_in, const int* in_sizes, int n_in,
                              void* d_out, int out_size, void* d_ws, size_t ws_size,
                              hipStream_t stream) {
    const float* x    = (const float*)d_in[0];
    const float* rw   = (const float*)d_in[1];
    const float* w1   = (const float*)d_in[2];
    const float* v1   = (const float*)d_in[3];
    const float* w2   = (const float*)d_in[4];
    const float* bias = (const float*)d_in[5];
    float* out = (float*)d_out;

    int T = in_sizes[0] / D_DIM;      // 4096
    int P = 2 * T;
    int maxMT = P / BM + E_NUM;       // 72

    char* p = (char*)d_ws;
    char* ws_end = p + ws_size;
    auto alloc = [&](size_t bytes) {
        char* r = p;
        p += (bytes + 255) & ~(size_t)255;
        return r;
    };
    unsigned short* xbf   = (unsigned short*)alloc((size_t)T * D_DIM * 2);
    int*   tk_idx     = (int*)alloc((size_t)T * 2 * 4);
    float* tk_w       = (float*)alloc((size_t)T * 2 * 4);
    int*   counts     = (int*)alloc(E_NUM * 4);
    int*   offsets    = (int*)alloc((E_NUM + 1) * 4);
    int*   tile_e     = (int*)alloc(maxMT * 4);
    int*   tile_row   = (int*)alloc(maxMT * 4);
    int*   n_mt       = (int*)alloc(4);
    int*   pair_token = (int*)alloc((size_t)P * 4);
    int*   pair_pos   = (int*)alloc((size_t)P * 4);
    unsigned short* hbf = (unsigned short*)alloc((size_t)P * F_DIM * 2);
    float* ypair      = (float*)alloc((size_t)P * D_DIM * 4);

    if (p > ws_end) {
        // workspace too small: emit a recognizable constant so the failure is diagnosable
        ws_too_small_kernel<<<(out_size + 255) / 256, 256, 0, stream>>>(out, out_size);
        return;
    }

    hipMemsetAsync(counts, 0, E_NUM * 4, stream);
    router_kernel<<<T, 64, 0, stream>>>(x, rw, xbf, tk_idx, tk_w, counts);
    scan_kernel<<<1, 64, 0, stream>>>(counts, offsets, tile_e, tile_row, n_mt);
    compact_kernel<<<E_NUM, 256, 0, stream>>>(tk_idx, offsets, pair_token, pair_pos, T);
    gemm1_glu_kernel<<<dim3(maxMT, F_DIM / BN), 256, 0, stream>>>(
        xbf, w1, v1, pair_token, offsets, tile_e, tile_row, n_mt, hbf);
    gemm2_kernel<<<dim3(maxMT, D_DIM / BN), 256, 0, stream>>>(
        hbf, w2, offsets, tile_e, tile_row, n_mt, ypair);
    combine_kernel<<<(T * D_DIM + 255) / 256, 256, 0, stream>>>(
        ypair, pair_pos, tk_w, bias, out, T * D_DIM);
}